// Round 9
// baseline (471.164 us; speedup 1.0000x reference)
//
#include <hip/hip_runtime.h>

#define NN 50000
#define NE 800000
#define INDIM 256
#define HIDD 128
#define ODIM 3
#define EDIM 4
#define NLAYERS 4

typedef __attribute__((ext_vector_type(8))) short bf16x8;
typedef __attribute__((ext_vector_type(4))) float f32x4;
typedef __attribute__((ext_vector_type(2))) float f32x2;

// round-to-nearest-even fp32 -> bf16 bits (finite inputs)
__device__ __forceinline__ ushort f2bf(float f) {
    unsigned int x = __float_as_uint(f);
    unsigned int r = (x + 0x7fffu + ((x >> 16) & 1u)) >> 16;
    return (ushort)r;
}
__device__ __forceinline__ float bf2f(ushort u) {
    return __uint_as_float(((unsigned int)u) << 16);
}
__device__ __forceinline__ float lo16f(unsigned int u) {
    return __uint_as_float(u << 16);
}
__device__ __forceinline__ float hi16f(unsigned int u) {
    return __uint_as_float(u & 0xffff0000u);
}

__device__ __forceinline__ bf16x8 loadA8(const ushort* p, bool ok) {
    if (ok) return *(const bf16x8*)p;
    bf16x8 z = {0, 0, 0, 0, 0, 0, 0, 0};
    return z;
}

// XCD-pairing swizzles (perf-only hints; correctness independent of mapping).
// 2 col-halves: grid 400
__device__ __forceinline__ bool swizzle400(int b, int& x, int& y) {
    x = (b >> 3) & 1;
    y = (b >> 4) * 8 + (b & 7);
    return y < 196;
}
// 4 col-quarters: grid 800
__device__ __forceinline__ bool swizzle800(int b, int& x, int& y) {
    x = (b >> 3) & 3;
    y = (b >> 5) * 8 + (b & 7);
    return y < 196;
}

// ---------------------------------------------------------------------------
// Weights-resident MFMA GEMM (bf16 hi/lo A in memory).
//   C = Ah@Bh + Ah@Bl + Al@Bh (+bias); B^T [n][k] staged to LDS once;
//   barrier-free k-loop; A frags straight from global (16B/lane coalesced).
// NJ=4 (64-col tiles): LDS 34.8 KB -> 4 blocks/CU -> all 784 blocks resident,
// no dispatch tail. 512 thr = 8 waves x 32 rows.
// ---------------------------------------------------------------------------
template<int NJ, int KSTEPS>
__global__ __launch_bounds__(512, 4) void gemm_wres(
    const ushort* __restrict__ Ah, const ushort* __restrict__ Al,
    const ushort* __restrict__ BTh, const ushort* __restrict__ BTl,
    const float* __restrict__ bias,
    ushort* __restrict__ Cb, int M, int lda, int ldc)
{
    constexpr int K  = KSTEPS * 32;
    constexpr int N  = NJ * 16;
    constexpr int KP = K + 8;                 // padded LDS stride (2-way alias = free)
    extern __shared__ ushort sB[];            // [2][N][KP]
    ushort* sBh = sB;
    ushort* sBl = sB + (size_t)N * KP;

    int bx, by;
    if (!swizzle800(blockIdx.x, bx, by)) return;

    const int tid     = threadIdx.x;
    const int colBase = bx * N;
    const ushort* Bh  = BTh + (size_t)colBase * K;
    const ushort* Bl  = BTl + (size_t)colBase * K;

    constexpr int KC8 = K / 8;
    for (int idx = tid; idx < N * KC8; idx += 512) {
        int n  = idx / KC8;
        int kc = idx % KC8;
        *(int4*)&sBh[n * KP + kc * 8] = *(const int4*)&Bh[(size_t)n * K + kc * 8];
        *(int4*)&sBl[n * KP + kc * 8] = *(const int4*)&Bl[(size_t)n * K + kc * 8];
    }
    __syncthreads();

    const int lane = tid & 63;
    const int wv   = tid >> 6;
    const int lm   = lane & 15, quad = lane >> 4;
    const int rowBase = by * 256 + wv * 32;

    f32x4 acc[2][NJ];
#pragma unroll
    for (int i = 0; i < 2; i++)
#pragma unroll
        for (int j = 0; j < NJ; j++)
#pragma unroll
            for (int t = 0; t < 4; t++) acc[i][j][t] = 0.f;

    for (int ks = 0; ks < KSTEPS; ks++) {
        const int ko = ks * 32 + quad * 8;
        bf16x8 ah[2], al[2];
#pragma unroll
        for (int i = 0; i < 2; i++) {
            int r = rowBase + i * 16 + lm;
            bool ok = r < M;
            size_t ao = (size_t)r * lda + ko;
            ah[i] = loadA8(&Ah[ao], ok);
            al[i] = loadA8(&Al[ao], ok);
        }
#pragma unroll
        for (int j = 0; j < NJ; j++) {
            int bo = (j * 16 + lm) * KP + ko;
            bf16x8 bh = *(const bf16x8*)&sBh[bo];
            bf16x8 bl = *(const bf16x8*)&sBl[bo];
            acc[0][j] = __builtin_amdgcn_mfma_f32_16x16x32_bf16(ah[0], bh, acc[0][j], 0, 0, 0);
            acc[1][j] = __builtin_amdgcn_mfma_f32_16x16x32_bf16(ah[1], bh, acc[1][j], 0, 0, 0);
            acc[0][j] = __builtin_amdgcn_mfma_f32_16x16x32_bf16(ah[0], bl, acc[0][j], 0, 0, 0);
            acc[1][j] = __builtin_amdgcn_mfma_f32_16x16x32_bf16(ah[1], bl, acc[1][j], 0, 0, 0);
            acc[0][j] = __builtin_amdgcn_mfma_f32_16x16x32_bf16(al[0], bh, acc[0][j], 0, 0, 0);
            acc[1][j] = __builtin_amdgcn_mfma_f32_16x16x32_bf16(al[1], bh, acc[1][j], 0, 0, 0);
        }
    }

    float bj[NJ];
#pragma unroll
    for (int j = 0; j < NJ; j++) bj[j] = bias ? bias[colBase + j * 16 + lm] : 0.f;

    // C/D layout: col = lane&15, row = quad*4 + reg
#pragma unroll
    for (int i = 0; i < 2; i++) {
#pragma unroll
        for (int t = 0; t < 4; t++) {
            int gr = rowBase + i * 16 + quad * 4 + t;
            if (gr < M) {
#pragma unroll
                for (int j = 0; j < NJ; j++) {
                    int gc = colBase + j * 16 + lm;
                    Cb[(size_t)gr * ldc + gc] = f2bf(acc[i][j][t] + bj[j]);
                }
            }
        }
    }
}

// ---------------------------------------------------------------------------
// In-projection GEMM: A is fp32 (h), hi/lo split done IN REGISTERS.
// Epilogue emits xh/xl exact hi/lo bf16 split. 392 useful blocks, all resident.
// ---------------------------------------------------------------------------
template<int NJ, int KSTEPS>
__global__ __launch_bounds__(512, 4) void gemm_wres_f32(
    const float* __restrict__ A,
    const ushort* __restrict__ BTh, const ushort* __restrict__ BTl,
    const float* __restrict__ bias,
    ushort* __restrict__ Eh, ushort* __restrict__ El,
    int M, int lda, int ldc)
{
    constexpr int K  = KSTEPS * 32;
    constexpr int N  = NJ * 16;
    constexpr int KP = K + 8;
    extern __shared__ ushort sB[];
    ushort* sBh = sB;
    ushort* sBl = sB + (size_t)N * KP;

    int bx, by;
    if (!swizzle400(blockIdx.x, bx, by)) return;

    const int tid     = threadIdx.x;
    const int colBase = bx * N;
    const ushort* Bh  = BTh + (size_t)colBase * K;
    const ushort* Bl  = BTl + (size_t)colBase * K;

    constexpr int KC8 = K / 8;
    for (int idx = tid; idx < N * KC8; idx += 512) {
        int n  = idx / KC8;
        int kc = idx % KC8;
        *(int4*)&sBh[n * KP + kc * 8] = *(const int4*)&Bh[(size_t)n * K + kc * 8];
        *(int4*)&sBl[n * KP + kc * 8] = *(const int4*)&Bl[(size_t)n * K + kc * 8];
    }
    __syncthreads();

    const int lane = tid & 63;
    const int wv   = tid >> 6;
    const int lm   = lane & 15, quad = lane >> 4;
    const int rowBase = by * 256 + wv * 32;

    f32x4 acc[2][NJ];
#pragma unroll
    for (int i = 0; i < 2; i++)
#pragma unroll
        for (int j = 0; j < NJ; j++)
#pragma unroll
            for (int t = 0; t < 4; t++) acc[i][j][t] = 0.f;

    for (int ks = 0; ks < KSTEPS; ks++) {
        const int ko = ks * 32 + quad * 8;
        bf16x8 ah[2], al[2];
#pragma unroll
        for (int i = 0; i < 2; i++) {
            int r = rowBase + i * 16 + lm;
            float v[8];
            if (r < M) {
                const float* ap = &A[(size_t)r * lda + ko];
                *(float4*)&v[0] = *(const float4*)ap;
                *(float4*)&v[4] = *(const float4*)(ap + 4);
            } else {
#pragma unroll
                for (int q = 0; q < 8; q++) v[q] = 0.f;
            }
#pragma unroll
            for (int q = 0; q < 8; q++) {
                ushort hi = f2bf(v[q]);
                ah[i][q] = (short)hi;
                al[i][q] = (short)f2bf(v[q] - bf2f(hi));
            }
        }
#pragma unroll
        for (int j = 0; j < NJ; j++) {
            int bo = (j * 16 + lm) * KP + ko;
            bf16x8 bh = *(const bf16x8*)&sBh[bo];
            bf16x8 bl = *(const bf16x8*)&sBl[bo];
            acc[0][j] = __builtin_amdgcn_mfma_f32_16x16x32_bf16(ah[0], bh, acc[0][j], 0, 0, 0);
            acc[1][j] = __builtin_amdgcn_mfma_f32_16x16x32_bf16(ah[1], bh, acc[1][j], 0, 0, 0);
            acc[0][j] = __builtin_amdgcn_mfma_f32_16x16x32_bf16(ah[0], bl, acc[0][j], 0, 0, 0);
            acc[1][j] = __builtin_amdgcn_mfma_f32_16x16x32_bf16(ah[1], bl, acc[1][j], 0, 0, 0);
            acc[0][j] = __builtin_amdgcn_mfma_f32_16x16x32_bf16(al[0], bh, acc[0][j], 0, 0, 0);
            acc[1][j] = __builtin_amdgcn_mfma_f32_16x16x32_bf16(al[1], bh, acc[1][j], 0, 0, 0);
        }
    }

    float bj[NJ];
#pragma unroll
    for (int j = 0; j < NJ; j++) bj[j] = bias ? bias[colBase + j * 16 + lm] : 0.f;

#pragma unroll
    for (int i = 0; i < 2; i++) {
#pragma unroll
        for (int t = 0; t < 4; t++) {
            int gr = rowBase + i * 16 + quad * 4 + t;
            if (gr < M) {
#pragma unroll
                for (int j = 0; j < NJ; j++) {
                    int gc = colBase + j * 16 + lm;
                    float v = acc[i][j][t] + bj[j];
                    size_t ci = (size_t)gr * ldc + gc;
                    ushort hi = f2bf(v);
                    Eh[ci] = hi;
                    El[ci] = f2bf(v - bf2f(hi));
                }
            }
        }
    }
}

// ---------------------------------------------------------------------------
// merged weight prep
// ---------------------------------------------------------------------------
__global__ void conv_weights(const float* __restrict__ Win, const float* __restrict__ Wm,
                             const float* __restrict__ bm,
                             ushort* __restrict__ winTh, ushort* __restrict__ winTl,
                             ushort* __restrict__ wzyTh, ushort* __restrict__ wzyTl,
                             float* __restrict__ b256) {
    int id = blockIdx.x * 256 + threadIdx.x;
    if (id < 32768) {
        int k = id >> 7, n = id & 127;
        float v = Win[id];
        ushort hi = f2bf(v);
        winTh[n * 256 + k] = hi;
        winTl[n * 256 + k] = f2bf(v - bf2f(hi));
    } else {
        int id2 = id - 32768;                  // 0..131071
        int l = id2 >> 15;
        int r = id2 & 32767;
        int n = r >> 7, k = r & 127;
        float v = (n < 128) ? Wm[l * 33280 + k * 128 + n]
                            : Wm[l * 33280 + (128 + k) * 128 + (n - 128)];
        ushort hi = f2bf(v);
        size_t o = (size_t)l * 32768 + (size_t)n * 128 + k;
        wzyTh[o] = hi;
        wzyTl[o] = f2bf(v - bf2f(hi));
        if (k == 0) b256[l * 256 + n] = (n < 128) ? 0.f : bm[l * 128 + (n - 128)];
    }
}

// ---------------------------------------------------------------------------
// CSR build: one atomic pass (deg+rank), scan, atomic-free scatter, gather
// ---------------------------------------------------------------------------
__global__ void histrank_kernel(const int* __restrict__ dst, int* __restrict__ deg,
                                int* __restrict__ rank) {
    int e = blockIdx.x * 256 + threadIdx.x;
    if (e < NE) rank[e] = atomicAdd(&deg[dst[e]], 1);
}

__global__ void scan1_kernel(const int* __restrict__ deg, int* __restrict__ csr,
                             int* __restrict__ bsum) {
    __shared__ int s[256];
    int t = threadIdx.x;
    int n = blockIdx.x * 256 + t;
    int v = (n < NN) ? deg[n] : 0;
    s[t] = v; __syncthreads();
    for (int d = 1; d < 256; d <<= 1) {
        int u = (t >= d) ? s[t - d] : 0;
        __syncthreads();
        s[t] += u;
        __syncthreads();
    }
    if (n < NN) csr[n] = s[t] - v;
    if (t == 255) bsum[blockIdx.x] = s[t];
}

__global__ void scan2_kernel(const int* __restrict__ bsum, int* __restrict__ boff) {
    __shared__ int s[256];
    int t = threadIdx.x;
    int v = (t < 196) ? bsum[t] : 0;
    s[t] = v; __syncthreads();
    for (int d = 1; d < 256; d <<= 1) {
        int u = (t >= d) ? s[t - d] : 0;
        __syncthreads();
        s[t] += u;
        __syncthreads();
    }
    boff[t] = s[t] - v;
}

__global__ void scan3_kernel(int* __restrict__ csr, const int* __restrict__ boff) {
    int n = blockIdx.x * 256 + threadIdx.x;
    if (n < NN) csr[n] += boff[blockIdx.x];
    if (n == 0) csr[NN] = NE;
}

__global__ void scatter_kernel(const int* __restrict__ dst, const int* __restrict__ rank,
                               const int* __restrict__ csr, int* __restrict__ eid) {
    int e = blockIdx.x * 256 + threadIdx.x;
    if (e < NE) eid[csr[dst[e]] + rank[e]] = e;
}

__global__ void gather_kernel(const int* __restrict__ eid, const int* __restrict__ src,
                              const float* __restrict__ ea,
                              int* __restrict__ srcS, float* __restrict__ eaS) {
    int p = blockIdx.x * 256 + threadIdx.x;
    if (p < NE) {
        int e = eid[p];
        srcS[p] = src[e];
        *(float4*)&eaS[(size_t)p * 4] = *(const float4*)&ea[(size_t)e * 4];
    }
}

// ---------------------------------------------------------------------------
// Aggregation (R7-proven shape): 4 nodes per wave (16 lanes/node, 8 ch/lane),
// 4-deep edge batches. Last layer fuses the output projection.
// ---------------------------------------------------------------------------
__global__ __launch_bounds__(256) void agg_kernel(
    const ushort* __restrict__ zy, const float* __restrict__ eaS,
    const float* __restrict__ W3,
    const int* __restrict__ srcS, const int* __restrict__ csr,
    ushort* __restrict__ xh, ushort* __restrict__ xl,
    const float* __restrict__ Wo, const float* __restrict__ bo,
    float* __restrict__ outp, int lastLayer)
{
    const int wv   = (blockIdx.x * 256 + threadIdx.x) >> 6;  // 0..12499
    const int lane = threadIdx.x & 63;
    const int g    = lane >> 4;          // node group 0..3
    const int li   = lane & 15;
    const int n    = wv * 4 + g;         // node id, exactly covers [0,50000)
    const int c0   = li * 8;             // channel base

    f32x2 w[4][4];
#pragma unroll
    for (int d = 0; d < 4; d++)
#pragma unroll
        for (int q2 = 0; q2 < 4; q2++) {
            float2 t = *(const float2*)&W3[d * HIDD + c0 + 2 * q2];
            w[d][q2] = {t.x, t.y};
        }

    uint4 yu = *(const uint4*)&zy[(size_t)n * 256 + 128 + c0];
    f32x2 y2[4] = {{lo16f(yu.x), hi16f(yu.x)}, {lo16f(yu.y), hi16f(yu.y)},
                   {lo16f(yu.z), hi16f(yu.z)}, {lo16f(yu.w), hi16f(yu.w)}};

    size_t xi = (size_t)n * HIDD + c0;
    uint4 uh = *(const uint4*)&xh[xi];
    uint4 ul = *(const uint4*)&xl[xi];
    f32x2 acc[4] = {{lo16f(uh.x) + lo16f(ul.x), hi16f(uh.x) + hi16f(ul.x)},
                    {lo16f(uh.y) + lo16f(ul.y), hi16f(uh.y) + hi16f(ul.y)},
                    {lo16f(uh.z) + lo16f(ul.z), hi16f(uh.z) + hi16f(ul.z)},
                    {lo16f(uh.w) + lo16f(ul.w), hi16f(uh.w) + hi16f(ul.w)}};

    int i = csr[n], end = csr[n + 1];

    for (; i + 4 <= end; i += 4) {
        int s0 = srcS[i], s1 = srcS[i + 1], s2 = srcS[i + 2], s3 = srcS[i + 3];
        uint4 z0 = *(const uint4*)&zy[(size_t)s0 * 256 + c0];
        uint4 z1 = *(const uint4*)&zy[(size_t)s1 * 256 + c0];
        uint4 z2 = *(const uint4*)&zy[(size_t)s2 * 256 + c0];
        uint4 z3 = *(const uint4*)&zy[(size_t)s3 * 256 + c0];
        float4 a0 = *(const float4*)&eaS[(size_t)(i + 0) * 4];
        float4 a1 = *(const float4*)&eaS[(size_t)(i + 1) * 4];
        float4 a2 = *(const float4*)&eaS[(size_t)(i + 2) * 4];
        float4 a3 = *(const float4*)&eaS[(size_t)(i + 3) * 4];
#pragma unroll
        for (int k = 0; k < 4; k++) {
            uint4  zk = (k == 0) ? z0 : (k == 1) ? z1 : (k == 2) ? z2 : z3;
            float4 ak = (k == 0) ? a0 : (k == 1) ? a1 : (k == 2) ? a2 : a3;
            const unsigned int zc[4] = {zk.x, zk.y, zk.z, zk.w};
#pragma unroll
            for (int q2 = 0; q2 < 4; q2++) {
                f32x2 m = {lo16f(zc[q2]), hi16f(zc[q2])};
                m += y2[q2];
                m += ak.x * w[0][q2];
                m += ak.y * w[1][q2];
                m += ak.z * w[2][q2];
                m += ak.w * w[3][q2];
                acc[q2].x += fmaxf(m.x, 0.f);
                acc[q2].y += fmaxf(m.y, 0.f);
            }
        }
    }
    for (; i < end; i++) {
        int sx = srcS[i];
        uint4 zk = *(const uint4*)&zy[(size_t)sx * 256 + c0];
        float4 ak = *(const float4*)&eaS[(size_t)i * 4];
        const unsigned int zc[4] = {zk.x, zk.y, zk.z, zk.w};
#pragma unroll
        for (int q2 = 0; q2 < 4; q2++) {
            f32x2 m = {lo16f(zc[q2]), hi16f(zc[q2])};
            m += y2[q2];
            m += ak.x * w[0][q2];
            m += ak.y * w[1][q2];
            m += ak.z * w[2][q2];
            m += ak.w * w[3][q2];
            acc[q2].x += fmaxf(m.x, 0.f);
            acc[q2].y += fmaxf(m.y, 0.f);
        }
    }

    if (!lastLayer) {
        uint4 oh, ol;
        unsigned int* ph = &oh.x;
        unsigned int* pl = &ol.x;
#pragma unroll
        for (int q2 = 0; q2 < 4; q2++) {
            ushort h0 = f2bf(acc[q2].x), h1 = f2bf(acc[q2].y);
            ushort l0 = f2bf(acc[q2].x - bf2f(h0)), l1 = f2bf(acc[q2].y - bf2f(h1));
            ph[q2] = (unsigned int)h0 | ((unsigned int)h1 << 16);
            pl[q2] = (unsigned int)l0 | ((unsigned int)l1 << 16);
        }
        *(uint4*)&xh[xi] = oh;
        *(uint4*)&xl[xi] = ol;
    } else {
        float p0 = 0.f, p1 = 0.f, p2 = 0.f;
#pragma unroll
        for (int q = 0; q < 8; q++) {
            float xv = (q & 1) ? acc[q >> 1].y : acc[q >> 1].x;
            int ch = c0 + q;
            p0 += xv * Wo[ch * ODIM + 0];
            p1 += xv * Wo[ch * ODIM + 1];
            p2 += xv * Wo[ch * ODIM + 2];
        }
#pragma unroll
        for (int off = 1; off < 16; off <<= 1) {
            p0 += __shfl_xor(p0, off);
            p1 += __shfl_xor(p1, off);
            p2 += __shfl_xor(p2, off);
        }
        if (li == 0) {
            outp[(size_t)n * ODIM + 0] = p0 + bo[0];
            outp[(size_t)n * ODIM + 1] = p1 + bo[1];
            outp[(size_t)n * ODIM + 2] = p2 + bo[2];
        }
    }
}

// ---------------------------------------------------------------------------
extern "C" void kernel_launch(void* const* d_in, const int* in_sizes, int n_in,
                              void* d_out, int out_size, void* d_ws, size_t ws_size,
                              hipStream_t stream)
{
    const float* h     = (const float*)d_in[0];
    const int*   ei    = (const int*)  d_in[1];
    const float* ea    = (const float*)d_in[2];
    const float* W_in  = (const float*)d_in[3];
    const float* b_in  = (const float*)d_in[4];
    const float* W_msg = (const float*)d_in[5];
    const float* b_msg = (const float*)d_in[6];
    const float* W_out = (const float*)d_in[7];
    const float* b_out = (const float*)d_in[8];
    float* out = (float*)d_out;

    // workspace carve-up (~81 MB)
    ushort* zy     = (ushort*)d_ws;                        // 12.8M us
    float*  eaS    = (float*)(zy + 12800000);              // 3.2M f
    int*    srcS   = (int*)(eaS + 3200000);                // 800k
    int*    eidArr = srcS + 800000;                        // 800k
    int*    rank   = eidArr + 800000;                      // 800k
    int*    deg    = rank + 800000;                        // 50176
    int*    csr    = deg + 50176;                          // NN+1 used
    int*    bsum   = csr + 50176;                          // 256
    int*    boff   = bsum + 256;                           // 256
    ushort* xh     = (ushort*)(boff + 256);                // 6.4M us
    ushort* xl     = xh + 6400000;                         // 6.4M us
    ushort* winTh  = xl + 6400000;                         // 32768
    ushort* winTl  = winTh + 32768;                        // 32768
    ushort* wzyTh  = winTl + 32768;                        // 131072
    ushort* wzyTl  = wzyTh + 131072;                       // 131072
    float*  bias256= (float*)(wzyTl + 131072);             // 1024 f

    const int* srcA = ei;        // edge_index[0]
    const int* dstA = ei + NE;   // edge_index[1]

    // allow >64KB dynamic LDS where needed (in-proj: 67.6 KB)
    hipFuncSetAttribute((const void*)&gemm_wres_f32<4, 8>,
                        hipFuncAttributeMaxDynamicSharedMemorySize, 2 * 64 * 264 * 2);

    // weight prep (merged)
    conv_weights<<<640, 256, 0, stream>>>(W_in, W_msg, b_msg,
                                          winTh, winTl, wzyTh, wzyTl, bias256);

    // CSR build
    hipMemsetAsync(deg, 0, 50176 * sizeof(int), stream);
    histrank_kernel<<<3125, 256, 0, stream>>>(dstA, deg, rank);
    scan1_kernel<<<196, 256, 0, stream>>>(deg, csr, bsum);
    scan2_kernel<<<1, 256, 0, stream>>>(bsum, boff);
    scan3_kernel<<<196, 256, 0, stream>>>(csr, boff);
    scatter_kernel<<<3125, 256, 0, stream>>>(dstA, rank, csr, eidArr);
    gather_kernel<<<3125, 256, 0, stream>>>(eidArr, srcA, ea, srcS, eaS);

    // input projection straight from fp32 h (in-register hi/lo split)
    gemm_wres_f32<4, 8><<<400, 512, 2 * 64 * 264 * 2, stream>>>(
        h, winTh, winTl, b_in, xh, xl, NN, INDIM, HIDD);

    for (int l = 0; l < NLAYERS; l++) {
        // zy GEMM: 64-col quarters, 34.8 KB LDS, 784 useful blocks all resident
        gemm_wres<4, 4><<<800, 512, 2 * 64 * 136 * 2, stream>>>(
            xh, xl, wzyTh + (size_t)l * 32768, wzyTl + (size_t)l * 32768,
            bias256 + l * 256, zy, NN, HIDD, 256);
        agg_kernel<<<3125, 256, 0, stream>>>(
            zy, eaS, W_msg + (size_t)l * 33280 + 256 * 128,
            srcS, csr, xh, xl, W_out, b_out, out,
            (l == NLAYERS - 1) ? 1 : 0);
    }
}

// Round 10
// 429.423 us; speedup vs baseline: 1.0972x; 1.0972x over previous
//
#include <hip/hip_runtime.h>

#define NN 50000
#define NE 800000
#define INDIM 256
#define HIDD 128
#define ODIM 3
#define EDIM 4
#define NLAYERS 4

typedef __attribute__((ext_vector_type(8))) short bf16x8;
typedef __attribute__((ext_vector_type(4))) float f32x4;
typedef __attribute__((ext_vector_type(2))) float f32x2;

// round-to-nearest-even fp32 -> bf16 bits (finite inputs)
__device__ __forceinline__ ushort f2bf(float f) {
    unsigned int x = __float_as_uint(f);
    unsigned int r = (x + 0x7fffu + ((x >> 16) & 1u)) >> 16;
    return (ushort)r;
}
__device__ __forceinline__ float bf2f(ushort u) {
    return __uint_as_float(((unsigned int)u) << 16);
}
__device__ __forceinline__ float lo16f(unsigned int u) {
    return __uint_as_float(u << 16);
}
__device__ __forceinline__ float hi16f(unsigned int u) {
    return __uint_as_float(u & 0xffff0000u);
}

__device__ __forceinline__ bf16x8 loadA8(const ushort* p, bool ok) {
    if (ok) return *(const bf16x8*)p;
    bf16x8 z = {0, 0, 0, 0, 0, 0, 0, 0};
    return z;
}

// XCD-pairing swizzle: grid 400, col-half pair 8 apart (perf-only hint)
__device__ __forceinline__ bool swizzle400(int b, int& x, int& y) {
    x = (b >> 3) & 1;
    y = (b >> 4) * 8 + (b & 7);
    return y < 196;
}

// ---------------------------------------------------------------------------
// Weights-resident MFMA GEMM, bf16 A (x state), 2-term exact-weight split:
//   C = A@Bh + A@Bl (+bias).  B^T [n][k] hi/lo staged to LDS once;
//   barrier-free k-loop; A frags from global (16B/lane coalesced).
// NJ=8: LDS 69.6 KB -> 2 blocks/CU, 392 useful blocks.
// ---------------------------------------------------------------------------
template<int NJ, int KSTEPS>
__global__ __launch_bounds__(512, 4) void gemm_wres(
    const ushort* __restrict__ Ah,
    const ushort* __restrict__ BTh, const ushort* __restrict__ BTl,
    const float* __restrict__ bias,
    ushort* __restrict__ Cb, int M, int lda, int ldc)
{
    constexpr int K  = KSTEPS * 32;
    constexpr int N  = NJ * 16;
    constexpr int KP = K + 8;                 // padded LDS stride (2-way alias = free)
    extern __shared__ ushort sB[];            // [2][N][KP]
    ushort* sBh = sB;
    ushort* sBl = sB + (size_t)N * KP;

    int bx, by;
    if (!swizzle400(blockIdx.x, bx, by)) return;

    const int tid     = threadIdx.x;
    const int colBase = bx * N;
    const ushort* Bh  = BTh + (size_t)colBase * K;
    const ushort* Bl  = BTl + (size_t)colBase * K;

    constexpr int KC8 = K / 8;
    for (int idx = tid; idx < N * KC8; idx += 512) {
        int n  = idx / KC8;
        int kc = idx % KC8;
        *(int4*)&sBh[n * KP + kc * 8] = *(const int4*)&Bh[(size_t)n * K + kc * 8];
        *(int4*)&sBl[n * KP + kc * 8] = *(const int4*)&Bl[(size_t)n * K + kc * 8];
    }
    __syncthreads();

    const int lane = tid & 63;
    const int wv   = tid >> 6;
    const int lm   = lane & 15, quad = lane >> 4;
    const int rowBase = by * 256 + wv * 32;

    f32x4 acc[2][NJ];
#pragma unroll
    for (int i = 0; i < 2; i++)
#pragma unroll
        for (int j = 0; j < NJ; j++)
#pragma unroll
            for (int t = 0; t < 4; t++) acc[i][j][t] = 0.f;

    for (int ks = 0; ks < KSTEPS; ks++) {
        const int ko = ks * 32 + quad * 8;
        bf16x8 ah[2];
#pragma unroll
        for (int i = 0; i < 2; i++) {
            int r = rowBase + i * 16 + lm;
            ah[i] = loadA8(&Ah[(size_t)r * lda + ko], r < M);
        }
#pragma unroll
        for (int j = 0; j < NJ; j++) {
            int bo = (j * 16 + lm) * KP + ko;
            bf16x8 bh = *(const bf16x8*)&sBh[bo];
            bf16x8 bl = *(const bf16x8*)&sBl[bo];
            acc[0][j] = __builtin_amdgcn_mfma_f32_16x16x32_bf16(ah[0], bh, acc[0][j], 0, 0, 0);
            acc[1][j] = __builtin_amdgcn_mfma_f32_16x16x32_bf16(ah[1], bh, acc[1][j], 0, 0, 0);
            acc[0][j] = __builtin_amdgcn_mfma_f32_16x16x32_bf16(ah[0], bl, acc[0][j], 0, 0, 0);
            acc[1][j] = __builtin_amdgcn_mfma_f32_16x16x32_bf16(ah[1], bl, acc[1][j], 0, 0, 0);
        }
    }

    float bj[NJ];
#pragma unroll
    for (int j = 0; j < NJ; j++) bj[j] = bias ? bias[colBase + j * 16 + lm] : 0.f;

    // C/D layout: col = lane&15, row = quad*4 + reg
#pragma unroll
    for (int i = 0; i < 2; i++) {
#pragma unroll
        for (int t = 0; t < 4; t++) {
            int gr = rowBase + i * 16 + quad * 4 + t;
            if (gr < M) {
#pragma unroll
                for (int j = 0; j < NJ; j++) {
                    int gc = colBase + j * 16 + lm;
                    Cb[(size_t)gr * ldc + gc] = f2bf(acc[i][j][t] + bj[j]);
                }
            }
        }
    }
}

// ---------------------------------------------------------------------------
// In-projection GEMM: A fp32 (h), exact in-register hi/lo split, 3 terms.
// Epilogue emits x state as bf16 (Eh only).
// ---------------------------------------------------------------------------
template<int NJ, int KSTEPS>
__global__ __launch_bounds__(512, 4) void gemm_wres_f32(
    const float* __restrict__ A,
    const ushort* __restrict__ BTh, const ushort* __restrict__ BTl,
    const float* __restrict__ bias,
    ushort* __restrict__ Eh, int M, int lda, int ldc)
{
    constexpr int K  = KSTEPS * 32;
    constexpr int N  = NJ * 16;
    constexpr int KP = K + 8;
    extern __shared__ ushort sB[];
    ushort* sBh = sB;
    ushort* sBl = sB + (size_t)N * KP;

    int bx, by;
    if (!swizzle400(blockIdx.x, bx, by)) return;

    const int tid     = threadIdx.x;
    const int colBase = bx * N;
    const ushort* Bh  = BTh + (size_t)colBase * K;
    const ushort* Bl  = BTl + (size_t)colBase * K;

    constexpr int KC8 = K / 8;
    for (int idx = tid; idx < N * KC8; idx += 512) {
        int n  = idx / KC8;
        int kc = idx % KC8;
        *(int4*)&sBh[n * KP + kc * 8] = *(const int4*)&Bh[(size_t)n * K + kc * 8];
        *(int4*)&sBl[n * KP + kc * 8] = *(const int4*)&Bl[(size_t)n * K + kc * 8];
    }
    __syncthreads();

    const int lane = tid & 63;
    const int wv   = tid >> 6;
    const int lm   = lane & 15, quad = lane >> 4;
    const int rowBase = by * 256 + wv * 32;

    f32x4 acc[2][NJ];
#pragma unroll
    for (int i = 0; i < 2; i++)
#pragma unroll
        for (int j = 0; j < NJ; j++)
#pragma unroll
            for (int t = 0; t < 4; t++) acc[i][j][t] = 0.f;

    for (int ks = 0; ks < KSTEPS; ks++) {
        const int ko = ks * 32 + quad * 8;
        bf16x8 ah[2], al[2];
#pragma unroll
        for (int i = 0; i < 2; i++) {
            int r = rowBase + i * 16 + lm;
            float v[8];
            if (r < M) {
                const float* ap = &A[(size_t)r * lda + ko];
                *(float4*)&v[0] = *(const float4*)ap;
                *(float4*)&v[4] = *(const float4*)(ap + 4);
            } else {
#pragma unroll
                for (int q = 0; q < 8; q++) v[q] = 0.f;
            }
#pragma unroll
            for (int q = 0; q < 8; q++) {
                ushort hi = f2bf(v[q]);
                ah[i][q] = (short)hi;
                al[i][q] = (short)f2bf(v[q] - bf2f(hi));
            }
        }
#pragma unroll
        for (int j = 0; j < NJ; j++) {
            int bo = (j * 16 + lm) * KP + ko;
            bf16x8 bh = *(const bf16x8*)&sBh[bo];
            bf16x8 bl = *(const bf16x8*)&sBl[bo];
            acc[0][j] = __builtin_amdgcn_mfma_f32_16x16x32_bf16(ah[0], bh, acc[0][j], 0, 0, 0);
            acc[1][j] = __builtin_amdgcn_mfma_f32_16x16x32_bf16(ah[1], bh, acc[1][j], 0, 0, 0);
            acc[0][j] = __builtin_amdgcn_mfma_f32_16x16x32_bf16(ah[0], bl, acc[0][j], 0, 0, 0);
            acc[1][j] = __builtin_amdgcn_mfma_f32_16x16x32_bf16(ah[1], bl, acc[1][j], 0, 0, 0);
            acc[0][j] = __builtin_amdgcn_mfma_f32_16x16x32_bf16(al[0], bh, acc[0][j], 0, 0, 0);
            acc[1][j] = __builtin_amdgcn_mfma_f32_16x16x32_bf16(al[1], bh, acc[1][j], 0, 0, 0);
        }
    }

    float bj[NJ];
#pragma unroll
    for (int j = 0; j < NJ; j++) bj[j] = bias ? bias[colBase + j * 16 + lm] : 0.f;

#pragma unroll
    for (int i = 0; i < 2; i++) {
#pragma unroll
        for (int t = 0; t < 4; t++) {
            int gr = rowBase + i * 16 + quad * 4 + t;
            if (gr < M) {
#pragma unroll
                for (int j = 0; j < NJ; j++) {
                    int gc = colBase + j * 16 + lm;
                    Eh[(size_t)gr * ldc + gc] = f2bf(acc[i][j][t] + bj[j]);
                }
            }
        }
    }
}

// ---------------------------------------------------------------------------
// merged weight prep
// ---------------------------------------------------------------------------
__global__ void conv_weights(const float* __restrict__ Win, const float* __restrict__ Wm,
                             const float* __restrict__ bm,
                             ushort* __restrict__ winTh, ushort* __restrict__ winTl,
                             ushort* __restrict__ wzyTh, ushort* __restrict__ wzyTl,
                             float* __restrict__ b256) {
    int id = blockIdx.x * 256 + threadIdx.x;
    if (id < 32768) {
        int k = id >> 7, n = id & 127;
        float v = Win[id];
        ushort hi = f2bf(v);
        winTh[n * 256 + k] = hi;
        winTl[n * 256 + k] = f2bf(v - bf2f(hi));
    } else {
        int id2 = id - 32768;                  // 0..131071
        int l = id2 >> 15;
        int r = id2 & 32767;
        int n = r >> 7, k = r & 127;
        float v = (n < 128) ? Wm[l * 33280 + k * 128 + n]
                            : Wm[l * 33280 + (128 + k) * 128 + (n - 128)];
        ushort hi = f2bf(v);
        size_t o = (size_t)l * 32768 + (size_t)n * 128 + k;
        wzyTh[o] = hi;
        wzyTl[o] = f2bf(v - bf2f(hi));
        if (k == 0) b256[l * 256 + n] = (n < 128) ? 0.f : bm[l * 128 + (n - 128)];
    }
}

// ---------------------------------------------------------------------------
// CSR build: one atomic pass (deg+rank), scan, atomic-free scatter, gather
// ---------------------------------------------------------------------------
__global__ void histrank_kernel(const int* __restrict__ dst, int* __restrict__ deg,
                                int* __restrict__ rank) {
    int e = blockIdx.x * 256 + threadIdx.x;
    if (e < NE) rank[e] = atomicAdd(&deg[dst[e]], 1);
}

__global__ void scan1_kernel(const int* __restrict__ deg, int* __restrict__ csr,
                             int* __restrict__ bsum) {
    __shared__ int s[256];
    int t = threadIdx.x;
    int n = blockIdx.x * 256 + t;
    int v = (n < NN) ? deg[n] : 0;
    s[t] = v; __syncthreads();
    for (int d = 1; d < 256; d <<= 1) {
        int u = (t >= d) ? s[t - d] : 0;
        __syncthreads();
        s[t] += u;
        __syncthreads();
    }
    if (n < NN) csr[n] = s[t] - v;
    if (t == 255) bsum[blockIdx.x] = s[t];
}

__global__ void scan2_kernel(const int* __restrict__ bsum, int* __restrict__ boff) {
    __shared__ int s[256];
    int t = threadIdx.x;
    int v = (t < 196) ? bsum[t] : 0;
    s[t] = v; __syncthreads();
    for (int d = 1; d < 256; d <<= 1) {
        int u = (t >= d) ? s[t - d] : 0;
        __syncthreads();
        s[t] += u;
        __syncthreads();
    }
    boff[t] = s[t] - v;
}

__global__ void scan3_kernel(int* __restrict__ csr, const int* __restrict__ boff) {
    int n = blockIdx.x * 256 + threadIdx.x;
    if (n < NN) csr[n] += boff[blockIdx.x];
    if (n == 0) csr[NN] = NE;
}

__global__ void scatter_kernel(const int* __restrict__ dst, const int* __restrict__ rank,
                               const int* __restrict__ csr, int* __restrict__ eid) {
    int e = blockIdx.x * 256 + threadIdx.x;
    if (e < NE) eid[csr[dst[e]] + rank[e]] = e;
}

__global__ void gather_kernel(const int* __restrict__ eid, const int* __restrict__ src,
                              const float* __restrict__ ea,
                              int* __restrict__ srcS, float* __restrict__ eaS) {
    int p = blockIdx.x * 256 + threadIdx.x;
    if (p < NE) {
        int e = eid[p];
        srcS[p] = src[e];
        *(float4*)&eaS[(size_t)p * 4] = *(const float4*)&ea[(size_t)e * 4];
    }
}

// ---------------------------------------------------------------------------
// Aggregation: 4 nodes/wave (16 lanes/node, 8 ch/lane), 4-deep batches.
// x state = bf16 (single array). Last layer fuses output projection.
// ---------------------------------------------------------------------------
__global__ __launch_bounds__(256) void agg_kernel(
    const ushort* __restrict__ zy, const float* __restrict__ eaS,
    const float* __restrict__ W3,
    const int* __restrict__ srcS, const int* __restrict__ csr,
    ushort* __restrict__ xh,
    const float* __restrict__ Wo, const float* __restrict__ bo,
    float* __restrict__ outp, int lastLayer)
{
    const int wv   = (blockIdx.x * 256 + threadIdx.x) >> 6;  // 0..12499
    const int lane = threadIdx.x & 63;
    const int g    = lane >> 4;          // node group 0..3
    const int li   = lane & 15;
    const int n    = wv * 4 + g;         // node id, exactly covers [0,50000)
    const int c0   = li * 8;             // channel base

    f32x2 w[4][4];
#pragma unroll
    for (int d = 0; d < 4; d++)
#pragma unroll
        for (int q2 = 0; q2 < 4; q2++) {
            float2 t = *(const float2*)&W3[d * HIDD + c0 + 2 * q2];
            w[d][q2] = {t.x, t.y};
        }

    uint4 yu = *(const uint4*)&zy[(size_t)n * 256 + 128 + c0];
    f32x2 y2[4] = {{lo16f(yu.x), hi16f(yu.x)}, {lo16f(yu.y), hi16f(yu.y)},
                   {lo16f(yu.z), hi16f(yu.z)}, {lo16f(yu.w), hi16f(yu.w)}};

    size_t xi = (size_t)n * HIDD + c0;
    uint4 uh = *(const uint4*)&xh[xi];
    f32x2 acc[4] = {{lo16f(uh.x), hi16f(uh.x)},
                    {lo16f(uh.y), hi16f(uh.y)},
                    {lo16f(uh.z), hi16f(uh.z)},
                    {lo16f(uh.w), hi16f(uh.w)}};

    int i = csr[n], end = csr[n + 1];

    for (; i + 4 <= end; i += 4) {
        int s0 = srcS[i], s1 = srcS[i + 1], s2 = srcS[i + 2], s3 = srcS[i + 3];
        uint4 z0 = *(const uint4*)&zy[(size_t)s0 * 256 + c0];
        uint4 z1 = *(const uint4*)&zy[(size_t)s1 * 256 + c0];
        uint4 z2 = *(const uint4*)&zy[(size_t)s2 * 256 + c0];
        uint4 z3 = *(const uint4*)&zy[(size_t)s3 * 256 + c0];
        float4 a0 = *(const float4*)&eaS[(size_t)(i + 0) * 4];
        float4 a1 = *(const float4*)&eaS[(size_t)(i + 1) * 4];
        float4 a2 = *(const float4*)&eaS[(size_t)(i + 2) * 4];
        float4 a3 = *(const float4*)&eaS[(size_t)(i + 3) * 4];
#pragma unroll
        for (int k = 0; k < 4; k++) {
            uint4  zk = (k == 0) ? z0 : (k == 1) ? z1 : (k == 2) ? z2 : z3;
            float4 ak = (k == 0) ? a0 : (k == 1) ? a1 : (k == 2) ? a2 : a3;
            const unsigned int zc[4] = {zk.x, zk.y, zk.z, zk.w};
#pragma unroll
            for (int q2 = 0; q2 < 4; q2++) {
                f32x2 m = {lo16f(zc[q2]), hi16f(zc[q2])};
                m += y2[q2];
                m += ak.x * w[0][q2];
                m += ak.y * w[1][q2];
                m += ak.z * w[2][q2];
                m += ak.w * w[3][q2];
                acc[q2].x += fmaxf(m.x, 0.f);
                acc[q2].y += fmaxf(m.y, 0.f);
            }
        }
    }
    for (; i < end; i++) {
        int sx = srcS[i];
        uint4 zk = *(const uint4*)&zy[(size_t)sx * 256 + c0];
        float4 ak = *(const float4*)&eaS[(size_t)i * 4];
        const unsigned int zc[4] = {zk.x, zk.y, zk.z, zk.w};
#pragma unroll
        for (int q2 = 0; q2 < 4; q2++) {
            f32x2 m = {lo16f(zc[q2]), hi16f(zc[q2])};
            m += y2[q2];
            m += ak.x * w[0][q2];
            m += ak.y * w[1][q2];
            m += ak.z * w[2][q2];
            m += ak.w * w[3][q2];
            acc[q2].x += fmaxf(m.x, 0.f);
            acc[q2].y += fmaxf(m.y, 0.f);
        }
    }

    if (!lastLayer) {
        uint4 oh;
        unsigned int* ph = &oh.x;
#pragma unroll
        for (int q2 = 0; q2 < 4; q2++) {
            ushort h0 = f2bf(acc[q2].x), h1 = f2bf(acc[q2].y);
            ph[q2] = (unsigned int)h0 | ((unsigned int)h1 << 16);
        }
        *(uint4*)&xh[xi] = oh;
    } else {
        float p0 = 0.f, p1 = 0.f, p2 = 0.f;
#pragma unroll
        for (int q = 0; q < 8; q++) {
            float xv = (q & 1) ? acc[q >> 1].y : acc[q >> 1].x;
            int ch = c0 + q;
            p0 += xv * Wo[ch * ODIM + 0];
            p1 += xv * Wo[ch * ODIM + 1];
            p2 += xv * Wo[ch * ODIM + 2];
        }
#pragma unroll
        for (int off = 1; off < 16; off <<= 1) {
            p0 += __shfl_xor(p0, off);
            p1 += __shfl_xor(p1, off);
            p2 += __shfl_xor(p2, off);
        }
        if (li == 0) {
            outp[(size_t)n * ODIM + 0] = p0 + bo[0];
            outp[(size_t)n * ODIM + 1] = p1 + bo[1];
            outp[(size_t)n * ODIM + 2] = p2 + bo[2];
        }
    }
}

// ---------------------------------------------------------------------------
extern "C" void kernel_launch(void* const* d_in, const int* in_sizes, int n_in,
                              void* d_out, int out_size, void* d_ws, size_t ws_size,
                              hipStream_t stream)
{
    const float* h     = (const float*)d_in[0];
    const int*   ei    = (const int*)  d_in[1];
    const float* ea    = (const float*)d_in[2];
    const float* W_in  = (const float*)d_in[3];
    const float* b_in  = (const float*)d_in[4];
    const float* W_msg = (const float*)d_in[5];
    const float* b_msg = (const float*)d_in[6];
    const float* W_out = (const float*)d_in[7];
    const float* b_out = (const float*)d_in[8];
    float* out = (float*)d_out;

    // workspace carve-up (~68 MB)
    ushort* zy     = (ushort*)d_ws;                        // 12.8M us
    float*  eaS    = (float*)(zy + 12800000);              // 3.2M f
    int*    srcS   = (int*)(eaS + 3200000);                // 800k
    int*    eidArr = srcS + 800000;                        // 800k
    int*    rank   = eidArr + 800000;                      // 800k
    int*    deg    = rank + 800000;                        // 50176
    int*    csr    = deg + 50176;                          // NN+1 used
    int*    bsum   = csr + 50176;                          // 256
    int*    boff   = bsum + 256;                           // 256
    ushort* xh     = (ushort*)(boff + 256);                // 6.4M us
    ushort* winTh  = xh + 6400000;                         // 32768
    ushort* winTl  = winTh + 32768;                        // 32768
    ushort* wzyTh  = winTl + 32768;                        // 131072
    ushort* wzyTl  = wzyTh + 131072;                       // 131072
    float*  bias256= (float*)(wzyTl + 131072);             // 1024 f

    const int* srcA = ei;        // edge_index[0]
    const int* dstA = ei + NE;   // edge_index[1]

    // allow >64KB dynamic LDS (in-proj 67.6 KB, zy GEMM 69.6 KB)
    hipFuncSetAttribute((const void*)&gemm_wres_f32<4, 8>,
                        hipFuncAttributeMaxDynamicSharedMemorySize, 2 * 64 * 264 * 2);
    hipFuncSetAttribute((const void*)&gemm_wres<8, 4>,
                        hipFuncAttributeMaxDynamicSharedMemorySize, 2 * 128 * 136 * 2);

    // weight prep (merged)
    conv_weights<<<640, 256, 0, stream>>>(W_in, W_msg, b_msg,
                                          winTh, winTl, wzyTh, wzyTl, bias256);

    // CSR build
    hipMemsetAsync(deg, 0, 50176 * sizeof(int), stream);
    histrank_kernel<<<3125, 256, 0, stream>>>(dstA, deg, rank);
    scan1_kernel<<<196, 256, 0, stream>>>(deg, csr, bsum);
    scan2_kernel<<<1, 256, 0, stream>>>(bsum, boff);
    scan3_kernel<<<196, 256, 0, stream>>>(csr, boff);
    scatter_kernel<<<3125, 256, 0, stream>>>(dstA, rank, csr, eidArr);
    gather_kernel<<<3125, 256, 0, stream>>>(eidArr, srcA, ea, srcS, eaS);

    // input projection straight from fp32 h (exact 3-term in-register split)
    gemm_wres_f32<4, 8><<<400, 512, 2 * 64 * 264 * 2, stream>>>(
        h, winTh, winTl, b_in, xh, NN, INDIM, HIDD);

    for (int l = 0; l < NLAYERS; l++) {
        // zy = x @ [W1|W2] + bias, 2-term (A bf16, weight hi/lo), NJ=8
        gemm_wres<8, 4><<<400, 512, 2 * 128 * 136 * 2, stream>>>(
            xh, wzyTh + (size_t)l * 32768, wzyTl + (size_t)l * 32768,
            bias256 + l * 256, zy, NN, HIDD, 256);
        agg_kernel<<<3125, 256, 0, stream>>>(
            zy, eaS, W_msg + (size_t)l * 33280 + 256 * 128,
            srcS, csr, xh, W_out, b_out, out,
            (l == NLAYERS - 1) ? 1 : 0);
    }
}